// Round 6
// baseline (121.209 us; speedup 1.0000x reference)
//
#include <hip/hip_runtime.h>

// SupConLoss, B=8192, D=128, T=5.0
// v7: triangle at 128x256 tiles (1056 blocks, 4 waves x 32 rows), direct-G
//     atomics (no Gp partials, no riders), per-group col-side atomic batching.
//   - tiles (bx,cy), cy <= bx>>1; (2k,k)+(2k+1,k) jointly = full diagonal block
//     (row-credit only, diag zeroed); below-tiles dual-credit row+col.
//   - part slots: row-side slot cy (plain store, single writer);
//     col-side slot 32+(bx>>1) (atomicAdd). Row i reads slots [0..c2] u
//     [32+c2+1..63], c2=i/256 -> exactly 32 slots, all written.
//   - max-free math: e = 2^(raw*invT*log2e - 40); m~ = ||f||^2/T in finalize.
//   - B tiles slot-linear in LDS (0 bank conflicts), 4-tile groups, 2 halves.

#define BN 8192
#define DK 128
#define INV_T 0.2f
#define C1F 0.28853901f     // INV_T * log2(e)
#define C40F 27.7258872f    // 40 * ln(2)

#define TILES 1056          // sum_{bx=0}^{63} (bx/2 + 1)
#define PSLOTS 64

#define NCLS 100
#define PB 128              // prep blocks
#define PROWS (BN / PB)     // 64

// workspace layout (bytes)
#define OFF_FB    0                                 // 2 MB bf16 features
#define OFF_PART  (2 * 1024 * 1024)                 // 2 MB float [PSLOTS][BN]
#define OFF_G     (OFF_PART + PSLOTS * BN * 4)      // 51.2 KB class sums
#define OFF_HIST  (OFF_G + NCLS * DK * 4)           // hist
#define OFF_BSUM  (OFF_HIST + 512)                  // block sums
#define OFF_CTR   (OFF_BSUM + 256)                  // arrival counter

typedef __attribute__((ext_vector_type(8))) short bf16x8;   // 8 bf16 = 4 VGPRs
typedef __attribute__((ext_vector_type(4))) float f32x4;

__device__ __forceinline__ unsigned short f2bf(float f) {
    unsigned u = __builtin_bit_cast(unsigned, f);
    u += 0x7fffu + ((u >> 16) & 1u);
    return (unsigned short)(u >> 16);
}

__device__ __forceinline__ float fexp2(float x) {
#if __has_builtin(__builtin_amdgcn_exp2f)
    return __builtin_amdgcn_exp2f(x);
#else
    float r; asm("v_exp_f32 %0, %1" : "=v"(r) : "v"(x)); return r;
#endif
}

__device__ __forceinline__ void load_lds16(const void* g, void* l) {
    __builtin_amdgcn_global_load_lds(
        (const __attribute__((address_space(1))) unsigned int*)g,
        (__attribute__((address_space(3))) unsigned int*)l, 16, 0, 0);
}

// zero G + hist + ctr (1 block) — must precede prep's atomics
__global__ __launch_bounds__(256) void zero_kernel(float* __restrict__ G,
                                                   int* __restrict__ hist,
                                                   unsigned int* __restrict__ ctr) {
    const int t = threadIdx.x;
    float4* g4 = (float4*)G;
#pragma unroll
    for (int k = 0; k < (NCLS * DK / 4 + 255) / 256; ++k) {   // 13
        const int idx = k * 256 + t;
        if (idx < NCLS * DK / 4) g4[idx] = make_float4(0.f, 0.f, 0.f, 0.f);
    }
    if (t < NCLS) hist[t] = 0;
    if (t == 0) *ctr = 0u;
}

// prep: cast to bf16, zero part, local class-sums -> atomicAdd into G/hist
__global__ __launch_bounds__(256) void prep_kernel(const float* __restrict__ F,
                                                   const int* __restrict__ labels,
                                                   unsigned short* __restrict__ Fb,
                                                   float* __restrict__ part,
                                                   float* __restrict__ G,
                                                   int* __restrict__ hist) {
    const int t  = threadIdx.x;
    const int b  = blockIdx.x;
    const int r0 = b * PROWS;

    // zero part: 2 MB / 128 blocks = 16 KB = 1024 float4 per block
    {
        float4* pz = (float4*)part + (size_t)b * (PSLOTS * BN / 4 / PB);
#pragma unroll
        for (int k = 0; k < PSLOTS * BN / 4 / PB / 256; ++k)   // 4
            pz[k * 256 + t] = make_float4(0.f, 0.f, 0.f, 0.f);
    }

    // cast: 64 rows = 2048 float4 per block
    const float4* F4  = (const float4*)F + (size_t)b * (PROWS * DK / 4);
    ushort4*      Fb4 = (ushort4*)Fb + (size_t)b * (PROWS * DK / 4);
#pragma unroll
    for (int k = 0; k < PROWS * DK / 4 / 256; ++k) {   // 8
        float4 v = F4[k * 256 + t];
        ushort4 o;
        o.x = f2bf(v.x); o.y = f2bf(v.y); o.z = f2bf(v.z); o.w = f2bf(v.w);
        Fb4[k * 256 + t] = o;
    }

    __shared__ int   ll[PROWS];
    __shared__ int   lh[NCLS];
    __shared__ float gl[2][NCLS][DK];   // 102.4 KB: two half-row partial tables
    float4* gl4 = (float4*)gl;
    if (t < NCLS) lh[t] = 0;
    if (t < PROWS) ll[t] = labels[r0 + t];
#pragma unroll
    for (int k = 0; k < 2 * NCLS * DK / 4 / 256; ++k)   // 25
        gl4[k * 256 + t] = make_float4(0.f, 0.f, 0.f, 0.f);
    __syncthreads();

    if (t < PROWS) atomicAdd(&lh[ll[t]], 1);

    // class-sum partials: 256 threads = 2 halves x 128 columns, 32 rows each
    {
        const int half = t >> 7, col = t & 127;
        const int rb   = half * (PROWS / 2);
        for (int rr = 0; rr < PROWS / 2; ++rr) {
            const int lr = rb + rr;
            gl[half][ll[lr]][col] += F[(size_t)(r0 + lr) * DK + col];
        }
    }
    __syncthreads();

    if (t < NCLS && lh[t]) atomicAdd(&hist[t], lh[t]);
    const float* gl0 = (const float*)gl;
#pragma unroll
    for (int k = 0; k < NCLS * DK / 256; ++k) {   // 50
        const int idx = k * 256 + t;
        const int c   = idx >> 7;
        if (lh[c]) atomicAdd(&G[idx], gl0[idx] + gl0[NCLS * DK + idx]);
    }
}

// one 128-row x 256-col tile at (bx, cy), cy <= bx>>1
template <bool DIAGT>
__device__ __forceinline__ void supcon_tile(const short* __restrict__ Fb,
                                            float* __restrict__ part,
                                            int bx, int cy, char* smem) {
    const int t    = threadIdx.x;
    const int wave = t >> 6, lane = t & 63;
    const int quad = lane >> 4, l16 = lane & 15;
    const int rowBase = bx * 128 + wave * 32;
    const int colBase = cy * 256;

    // slot-linear LDS B tiles (4 KB each): slot s=(kt*4+quad)*16+col holds
    // Fb[colBase+jt*16+col][kt*32+quad*8 ..+8]; per-lane pre-permuted GLOBAL
    // source, linear LDS dest (rule #21) -> conflict-free b128 reads.
    const char* Btile = (const char*)Fb + (size_t)colBase * 256;
    const int   gso   = (t & 15) * 256 + (t >> 6) * 64 + ((t >> 4) & 3) * 16;
    char*       ldsw  = smem + wave * 1024;

    // stage group 0 (tiles 0..3) into half 0
#pragma unroll
    for (int tt = 0; tt < 4; ++tt)
        load_lds16(Btile + tt * 4096 + gso, ldsw + tt * 4096);

    // A fragments: 32 rows x K=128 per wave
    bf16x8 a[2][4];
#pragma unroll
    for (int rt = 0; rt < 2; ++rt)
#pragma unroll
        for (int kt = 0; kt < 4; ++kt)
            a[rt][kt] = *(const bf16x8*)(Fb + (size_t)(rowBase + rt * 16 + l16) * DK
                                            + kt * 32 + quad * 8);

    float Zs[2][4];
#pragma unroll
    for (int rt = 0; rt < 2; ++rt)
#pragma unroll
        for (int r = 0; r < 4; ++r) Zs[rt][r] = 0.f;
    float Zcol[4];   // col-side batch for the current group (static idx)

    const int    roffb   = quad * 256 + l16 * 16;
    float* const colpart = part + (size_t)(32 + (bx >> 1)) * BN + colBase;

    __syncthreads();   // group 0 staged

#pragma unroll
    for (int g = 0; g < 4; ++g) {
        if (g < 3) {   // stage next group into the other half
            char* dsth = smem + ((g + 1) & 1) * 16384 + wave * 1024;
#pragma unroll
            for (int tt = 0; tt < 4; ++tt)
                load_lds16(Btile + (size_t)((g + 1) * 4 + tt) * 4096 + gso,
                           dsth + tt * 4096);
        }
        const char* srch = smem + (g & 1) * 16384;
#pragma unroll
        for (int tt = 0; tt < 4; ++tt) {
            const int jt = g * 4 + tt;
            bf16x8 bb[4];
#pragma unroll
            for (int kt = 0; kt < 4; ++kt)
                bb[kt] = *(const bf16x8*)(srch + tt * 4096 + kt * 1024 + roffb);
            float Zc0 = 0.f, Zc1 = 0.f;
#pragma unroll
            for (int rt = 0; rt < 2; ++rt) {
                f32x4 acc = {0.f, 0.f, 0.f, 0.f};
#pragma unroll
                for (int kt = 0; kt < 4; ++kt)
                    acc = __builtin_amdgcn_mfma_f32_16x16x32_bf16(a[rt][kt], bb[kt],
                                                                  acc, 0, 0, 0);
#pragma unroll
                for (int r = 0; r < 4; ++r) {
                    float e = fexp2(fmaf(acc[r], C1F, -40.0f));
                    if (DIAGT) {
                        if (colBase + jt * 16 + l16 == rowBase + rt * 16 + quad * 4 + r)
                            e = 0.f;                       // Z excludes diagonal
                    }
                    Zs[rt][r] += e;                        // row-side
                    if (!DIAGT) { if (rt == 0) Zc0 += e; else Zc1 += e; }
                }
            }
            if (!DIAGT) {   // reduce over the 4 quads (this wave's 32 rows)
                float Zc = Zc0 + Zc1;
                Zc += __shfl_xor(Zc, 16);
                Zc += __shfl_xor(Zc, 32);
                Zcol[tt] = Zc;
            }
        }
        if (g < 3) __syncthreads();   // next half staged; this half reusable
        // col-side atomics for group g issued AFTER the barrier: they fly
        // under the next group's compute; drained harmlessly at the next sync.
        if (!DIAGT && quad == 0) {
#pragma unroll
            for (int tt = 0; tt < 4; ++tt)
                atomicAdd(colpart + (g * 4 + tt) * 16 + l16, Zcol[tt]);
        }
    }

    // row-side: slot cy single-writer across the grid -> plain store
#pragma unroll
    for (int rt = 0; rt < 2; ++rt)
#pragma unroll
        for (int r = 0; r < 4; ++r) {
            float zz = Zs[rt][r];
#pragma unroll
            for (int h = 1; h < 16; h <<= 1) zz += __shfl_xor(zz, h);
            if (l16 == 0)
                part[(size_t)cy * BN + rowBase + rt * 16 + quad * 4 + r] = zz;
        }
}

__global__ __launch_bounds__(256) void supcon_main(const short* __restrict__ Fb,
                                                   float* __restrict__ part) {
    __shared__ alignas(16) char smem[32768];
    const int bid = blockIdx.x;
    // decode: S(2k)=k^2+k, S(2k+1)=(k+1)^2; ranges [k^2,k^2+k)->bx=2k-1,
    // [k^2+k,(k+1)^2)->bx=2k
    int k0 = (int)sqrtf((float)bid);
    while ((k0 + 1) * (k0 + 1) <= bid) ++k0;
    while (k0 * k0 > bid) --k0;
    int bx, cy;
    if (bid < k0 * k0 + k0) { bx = 2 * k0 - 1; cy = bid - k0 * k0; }
    else                    { bx = 2 * k0;     cy = bid - k0 * k0 - k0; }
    if (cy == (bx >> 1)) supcon_tile<true >(Fb, part, bx, cy, smem);
    else                 supcon_tile<false>(Fb, part, bx, cy, smem);
}

__global__ __launch_bounds__(256) void supcon_finalize(const float* __restrict__ F,
                                                       const int* __restrict__ labels,
                                                       const float* __restrict__ part,
                                                       const float* __restrict__ G,
                                                       const int* __restrict__ hist,
                                                       float* __restrict__ bsums,
                                                       unsigned int* __restrict__ ctr,
                                                       float* __restrict__ out) {
    const int t  = threadIdx.x;
    const int i  = blockIdx.x * 256 + t;
    const int c2 = blockIdx.x;   // i/256, block-uniform

    // row i's Z: row-side slots [0..c2], col-side slots [32+c2+1..63] = 32 reads
    float Zm = 0.f;
#pragma unroll 8
    for (int k = 0; k < 32; ++k) {
        const int slot = (k <= c2) ? k : 32 + k;
        Zm += part[(size_t)slot * BN + i];
    }

    const int   lbl = labels[i];
    const float cnt = (float)(hist[lbl] - 1);

    const float4* fr = (const float4*)(F + (size_t)i * DK);
    const float4* gr = (const float4*)(G + lbl * DK);
    float dot = 0.f, nrm = 0.f;
#pragma unroll 8
    for (int k = 0; k < DK / 4; ++k) {
        const float4 av = fr[k], gv = gr[k];
        dot += av.x * gv.x + av.y * gv.y + av.z * gv.z + av.w * gv.w;
        nrm += av.x * av.x + av.y * av.y + av.z * av.z + av.w * av.w;
    }

    // m~ = s_ii/T; exact for any m~ (m only enters via the 1e-12 term)
    const float mt = nrm * INV_T;
    const float A  = (dot - nrm) * INV_T;
    float term = 0.f;
    if (cnt > 0.5f)
        term = (A - cnt * mt) / cnt - __logf(1e-12f + Zm * __expf(C40F - mt));

    float sum = term;
#pragma unroll
    for (int h = 1; h < 64; h <<= 1) sum += __shfl_xor(sum, h);
    __shared__ float ss[4];
    if ((t & 63) == 0) ss[t >> 6] = sum;
    __syncthreads();
    if (t == 0) {
        bsums[blockIdx.x] = ss[0] + ss[1] + ss[2] + ss[3];
        __threadfence();
        const unsigned old = atomicAdd(ctr, 1u);
        if (old == (BN / 256) - 1) {   // last block folds the final reduction
            __threadfence();
            float tot = 0.f;
            const volatile float* vb = bsums;
            for (int c = 0; c < BN / 256; ++c) tot += vb[c];
            out[0] = -tot * (1.0f / BN);
        }
    }
}

extern "C" void kernel_launch(void* const* d_in, const int* in_sizes, int n_in,
                              void* d_out, int out_size, void* d_ws, size_t ws_size,
                              hipStream_t stream) {
    const float* F      = (const float*)d_in[0];
    const int*   labels = (const int*)d_in[1];
    // d_in[2] (fac_label) is a no-op in the reference math.
    float* out = (float*)d_out;
    char*  ws  = (char*)d_ws;

    unsigned short* Fb    = (unsigned short*)(ws + OFF_FB);
    float*          part  = (float*)(ws + OFF_PART);
    float*          G     = (float*)(ws + OFF_G);
    int*            hist  = (int*)(ws + OFF_HIST);
    float*          bsums = (float*)(ws + OFF_BSUM);
    unsigned int*   ctr   = (unsigned int*)(ws + OFF_CTR);

    zero_kernel<<<1, 256, 0, stream>>>(G, hist, ctr);
    prep_kernel<<<PB, 256, 0, stream>>>(F, labels, Fb, part, G, hist);
    supcon_main<<<TILES, 256, 0, stream>>>((const short*)Fb, part);
    supcon_finalize<<<BN / 256, 256, 0, stream>>>(F, labels, part, G, hist,
                                                  bsums, ctr, out);
}